// Round 13
// baseline (390.057 us; speedup 1.0000x reference)
//
#include <hip/hip_runtime.h>

#define B_ 256
#define T_ 1024
#define V_ 5000
#define D_ 100
#define H_ 64
#define C_ 2

typedef float f32x4v __attribute__((ext_vector_type(4)));
typedef short bf16x8 __attribute__((ext_vector_type(8)));

#define SCALE_ 2.885390081777927f   // 2*log2(e): exp2(SCALE*x) == e^{2x}

// ---------------------------------------------------------------------------
// Kernel 1: EW[v][h] = 2*log2e*(sum_d E[v][d]*W[d][h] + b[h])   (unchanged)
// ---------------------------------------------------------------------------
__global__ __launch_bounds__(256) void ew_kernel(const float* __restrict__ E,
                                                 const float* __restrict__ W,
                                                 const float* __restrict__ bias,
                                                 float* __restrict__ EW) {
    int idx = blockIdx.x * 256 + threadIdx.x;   // 0 .. V_*H_
    if (idx >= V_ * H_) return;
    int h = idx & (H_ - 1);
    int v = idx >> 6;
    float acc = bias[h];
    const float* Erow = E + v * D_;
    #pragma unroll 4
    for (int d = 0; d < D_; ++d) {
        acc = fmaf(Erow[d], W[d * H_ + h], acc);
    }
    EW[idx] = SCALE_ * acc;
}

// ---------------------------------------------------------------------------
// Kernel 2: RNN. R17: MFMA step. y = h.U via mfma_f32_16x16x32_bf16.
//  - hi/lo bf16 split of BOTH h and U; products hi*hi + lo*hi + hi*lo
//    (lo*lo dropped) => ~1e-5 error, fp32-class.
//  - A = h replicated in ALL 16 rows (every lane supplies h[k] for its
//    k-group): row-mapping-proof, and D = y in every row/reg => lane j
//    selects its own acc[j>>4][0] (col=j&15) -- NO output redistribution.
//  - k-mapping per m156/m162 (tr-read<->MFMA): elem e of lane l is
//    k = 16*(e>>2) + 4*(l>>4) + (e&3); fragment words hold CONSECUTIVE
//    k-pairs => A-fragments come straight from contiguous bf16 arrays in
//    LDS via 8x ds_read_b64 (zero pack VALU).
//  - per step: 4 VALU split + 2 ds_write_b16 + 8 ds_read_b64 + 24 MFMA
//    (4 indep chains of 6, reuse distance 4) + 3 cndmask + tanh tail.
//    Est. ~350-450 cyc vs R10's 583.
//  - B fragments (64 VGPRs) built once, pinned with the R10-proven
//    multi-operand "+v" pin (init) + "v" uses (in-loop).
// Pre-commit: fail or >= 318.7us total => revert R10 + ROOFLINE.
// ---------------------------------------------------------------------------
__global__ __launch_bounds__(64, 1) void rnn_kernel(const int* __restrict__ tokens,
                                                    const float* __restrict__ EW,
                                                    const float* __restrict__ U,
                                                    const float* __restrict__ Wd,
                                                    const float* __restrict__ bd,
                                                    float* __restrict__ out) {
    const int b = blockIdx.x;       // batch element
    const int j = threadIdx.x;      // 0..63 : hidden unit
    const int g = j >> 4;           // k-group (lane>>4) for MFMA fragments
    const int c = j & 15;           // col within a 16-wide N-tile

    __shared__ int sh_tok[T_ + 2];                  // 4 KB + pad
    __shared__ alignas(8) unsigned short sh_hhi[H_];  // h hi-bf16, 128 B
    __shared__ alignas(8) unsigned short sh_hlo[H_];  // h lo-bf16, 128 B

    // ---- B fragments: Bhi[t][s], Blo[t][s]  (t = N-tile, s = K-half) ----
    // B[k][n] = SCALE*U[k][16t+n]; lane elem e: k = 32s+16*(e>>2)+4g+(e&3), n=c.
    // Word w holds consecutive pair k0=32s+16*(w>>1)+4g+2*(w&1), k0+1.
    union BF { unsigned u[4]; bf16x8 v; };
    BF bhi[4][2], blo[4][2];
    #pragma unroll
    for (int t = 0; t < 4; ++t) {
        #pragma unroll
        for (int s = 0; s < 2; ++s) {
            #pragma unroll
            for (int w = 0; w < 4; ++w) {
                int k0 = 32 * s + 16 * (w >> 1) + 4 * g + 2 * (w & 1);
                float u0 = SCALE_ * U[(k0 + 0) * H_ + 16 * t + c];
                float u1 = SCALE_ * U[(k0 + 1) * H_ + 16 * t + c];
                unsigned c0, c1, e0, e1;
                // cvt_pk(x,x): both halves = bf16(x) -> operand-order-proof
                asm("v_cvt_pk_bf16_f32 %0, %1, %2" : "=v"(c0) : "v"(u0), "v"(u0));
                asm("v_cvt_pk_bf16_f32 %0, %1, %2" : "=v"(c1) : "v"(u1), "v"(u1));
                c0 &= 0xffffu; c1 &= 0xffffu;
                float d0 = u0 - __uint_as_float(c0 << 16);
                float d1 = u1 - __uint_as_float(c1 << 16);
                asm("v_cvt_pk_bf16_f32 %0, %1, %2" : "=v"(e0) : "v"(d0), "v"(d0));
                asm("v_cvt_pk_bf16_f32 %0, %1, %2" : "=v"(e1) : "v"(d1), "v"(d1));
                bhi[t][s].u[w] = c0 | (c1 << 16);
                blo[t][s].u[w] = (e0 & 0xffffu) | (e1 << 16);
            }
        }
    }
    // init pins: all fragments live at once (two groups of 16 regs x 4)
    asm volatile("" : "+v"(bhi[0][0].v), "+v"(bhi[0][1].v), "+v"(bhi[1][0].v),
                      "+v"(bhi[1][1].v), "+v"(bhi[2][0].v), "+v"(bhi[2][1].v),
                      "+v"(bhi[3][0].v), "+v"(bhi[3][1].v));
    asm volatile("" : "+v"(blo[0][0].v), "+v"(blo[0][1].v), "+v"(blo[1][0].v),
                      "+v"(blo[1][1].v), "+v"(blo[2][0].v), "+v"(blo[2][1].v),
                      "+v"(blo[3][0].v), "+v"(blo[3][1].v));

    const int* tok = tokens + b * T_;
    #pragma unroll
    for (int k = 0; k < T_ / H_; ++k) {
        sh_tok[k * H_ + j] = tok[k * H_ + j];    // coalesced
    }
    if (j < 2) sh_tok[T_ + j] = 0;               // pad
    __syncthreads();

    const uint2* hhi64 = (const uint2*)sh_hhi;   // b64 views (k-pairs x2)
    const uint2* hlo64 = (const uint2*)sh_hlo;

    float h = 0.f;
    float pooled = 0.f;

    // 2-step-deep xw prefetch pipeline (covers L2 latency of EW gather)
    int2 tkA = *(const int2*)&sh_tok[0];
    float xw0 = EW[tkA.x * H_ + j];
    float xw1 = EW[tkA.y * H_ + j];

    #define MFMA_(a, bb, cc) __builtin_amdgcn_mfma_f32_16x16x32_bf16((a), (bb), (cc), 0, 0, 0)

    // one recurrence step: bf16-split h -> LDS -> A-frags -> 24 MFMA -> tanh
    #define RNN_STEP(tokv, xwv)                                               \
    {                                                                         \
        unsigned whi_, wlo_;                                                  \
        asm("v_cvt_pk_bf16_f32 %0, %1, %2" : "=v"(whi_) : "v"(h), "v"(h));    \
        float dlo_ = h - __uint_as_float(whi_ << 16);                         \
        asm("v_cvt_pk_bf16_f32 %0, %1, %2" : "=v"(wlo_) : "v"(dlo_), "v"(dlo_)); \
        sh_hhi[j] = (unsigned short)whi_;                                     \
        sh_hlo[j] = (unsigned short)wlo_;                                     \
        asm volatile("" ::: "memory");  /* order LDS reads after writes */    \
        uint2 h0_ = hhi64[g];      uint2 h1_ = hhi64[4 + g];                  \
        uint2 h2_ = hhi64[8 + g];  uint2 h3_ = hhi64[12 + g];                 \
        uint2 l0_ = hlo64[g];      uint2 l1_ = hlo64[4 + g];                  \
        uint2 l2_ = hlo64[8 + g];  uint2 l3_ = hlo64[12 + g];                 \
        BF ahi0_, ahi1_, alo0_, alo1_;                                        \
        ahi0_.u[0] = h0_.x; ahi0_.u[1] = h0_.y;                               \
        ahi0_.u[2] = h1_.x; ahi0_.u[3] = h1_.y;                               \
        ahi1_.u[0] = h2_.x; ahi1_.u[1] = h2_.y;                               \
        ahi1_.u[2] = h3_.x; ahi1_.u[3] = h3_.y;                               \
        alo0_.u[0] = l0_.x; alo0_.u[1] = l0_.y;                               \
        alo0_.u[2] = l1_.x; alo0_.u[3] = l1_.y;                               \
        alo1_.u[0] = l2_.x; alo1_.u[1] = l2_.y;                               \
        alo1_.u[2] = l3_.x; alo1_.u[3] = l3_.y;                               \
        f32x4v z_ = {0.f, 0.f, 0.f, 0.f};                                     \
        f32x4v a0_ = MFMA_(ahi0_.v, bhi[0][0].v, z_);                         \
        f32x4v a1_ = MFMA_(ahi0_.v, bhi[1][0].v, z_);                         \
        f32x4v a2_ = MFMA_(ahi0_.v, bhi[2][0].v, z_);                         \
        f32x4v a3_ = MFMA_(ahi0_.v, bhi[3][0].v, z_);                         \
        a0_ = MFMA_(ahi1_.v, bhi[0][1].v, a0_);                               \
        a1_ = MFMA_(ahi1_.v, bhi[1][1].v, a1_);                               \
        a2_ = MFMA_(ahi1_.v, bhi[2][1].v, a2_);                               \
        a3_ = MFMA_(ahi1_.v, bhi[3][1].v, a3_);                               \
        a0_ = MFMA_(alo0_.v, bhi[0][0].v, a0_);                               \
        a1_ = MFMA_(alo0_.v, bhi[1][0].v, a1_);                               \
        a2_ = MFMA_(alo0_.v, bhi[2][0].v, a2_);                               \
        a3_ = MFMA_(alo0_.v, bhi[3][0].v, a3_);                               \
        a0_ = MFMA_(alo1_.v, bhi[0][1].v, a0_);                               \
        a1_ = MFMA_(alo1_.v, bhi[1][1].v, a1_);                               \
        a2_ = MFMA_(alo1_.v, bhi[2][1].v, a2_);                               \
        a3_ = MFMA_(alo1_.v, bhi[3][1].v, a3_);                               \
        a0_ = MFMA_(ahi0_.v, blo[0][0].v, a0_);                               \
        a1_ = MFMA_(ahi0_.v, blo[1][0].v, a1_);                               \
        a2_ = MFMA_(ahi0_.v, blo[2][0].v, a2_);                               \
        a3_ = MFMA_(ahi0_.v, blo[3][0].v, a3_);                               \
        a0_ = MFMA_(ahi1_.v, blo[0][1].v, a0_);                               \
        a1_ = MFMA_(ahi1_.v, blo[1][1].v, a1_);                               \
        a2_ = MFMA_(ahi1_.v, blo[2][1].v, a2_);                               \
        a3_ = MFMA_(ahi1_.v, blo[3][1].v, a3_);                               \
        float ya_ = (j & 16) ? a1_[0] : a0_[0];                               \
        float yb_ = (j & 16) ? a3_[0] : a2_[0];                               \
        float y_  = (j & 32) ? yb_ : ya_;                                     \
        float x2_ = y_ + (xwv);                                               \
        float ef_ = __builtin_amdgcn_exp2f(x2_);                              \
        float r_  = __builtin_amdgcn_rcpf(ef_ + 1.f);                         \
        float hn_ = fmaf(-2.f, r_, 1.f);                                      \
        h = ((tokv) != 0) ? hn_ : h;                                          \
        pooled += h;                                                          \
    }

    for (int t = 0; t < T_; t += 2) {
        // in-loop pins: spilling any fragment would force an in-loop reload
        asm volatile("" :: "v"(bhi[0][0].v), "v"(bhi[0][1].v), "v"(bhi[1][0].v),
                           "v"(bhi[1][1].v), "v"(bhi[2][0].v), "v"(bhi[2][1].v),
                           "v"(bhi[3][0].v), "v"(bhi[3][1].v));
        asm volatile("" :: "v"(blo[0][0].v), "v"(blo[0][1].v), "v"(blo[1][0].v),
                           "v"(blo[1][1].v), "v"(blo[2][0].v), "v"(blo[2][1].v),
                           "v"(blo[3][0].v), "v"(blo[3][1].v));

        // prefetch steps t+2, t+3 (pad makes the tail read safe: EW[0])
        int2 tkB = *(const int2*)&sh_tok[t + 2];
        float xw2 = EW[tkB.x * H_ + j];
        float xw3 = EW[tkB.y * H_ + j];

        RNN_STEP(tkA.x, xw0);
        RNN_STEP(tkA.y, xw1);

        tkA = tkB;
        xw0 = xw2;
        xw1 = xw3;
    }
    #undef RNN_STEP
    #undef MFMA_

    // ---- epilogue: pooled mean -> dense(2) -> sigmoid ----
    float p = pooled * (1.0f / (float)T_);
    float v0 = p * Wd[j * C_ + 0];
    float v1 = p * Wd[j * C_ + 1];
    #pragma unroll
    for (int off = 32; off >= 1; off >>= 1) {
        v0 += __shfl_down(v0, off, 64);
        v1 += __shfl_down(v1, off, 64);
    }
    if (j == 0) {
        float l0 = v0 + bd[0];
        float l1 = v1 + bd[1];
        out[b * C_ + 0] = 1.f / (1.f + __expf(-l0));
        out[b * C_ + 1] = 1.f / (1.f + __expf(-l1));
    }
}

// ---------------------------------------------------------------------------
extern "C" void kernel_launch(void* const* d_in, const int* in_sizes, int n_in,
                              void* d_out, int out_size, void* d_ws, size_t ws_size,
                              hipStream_t stream) {
    const int*   tokens = (const int*)  d_in[0];  // [B,T] int32
    const float* E      = (const float*)d_in[1];  // [V,D]
    const float* W      = (const float*)d_in[2];  // [D,H]
    const float* U      = (const float*)d_in[3];  // [H,H]
    const float* bias   = (const float*)d_in[4];  // [H]
    const float* Wd     = (const float*)d_in[5];  // [H,C]
    const float* bd     = (const float*)d_in[6];  // [C]
    float* out = (float*)d_out;                   // [B,C]
    float* EW  = (float*)d_ws;                    // [V,H] scratch: 1.28 MB

    ew_kernel<<<(V_ * H_ + 255) / 256, 256, 0, stream>>>(E, W, bias, EW);
    rnn_kernel<<<B_, H_, 0, stream>>>(tokens, EW, U, Wd, bd, out);
}

// Round 14
// 317.504 us; speedup vs baseline: 1.2285x; 1.2285x over previous
//
#include <hip/hip_runtime.h>

#define B_ 256
#define T_ 1024
#define V_ 5000
#define D_ 100
#define H_ 64
#define C_ 2

typedef float f32x4 __attribute__((ext_vector_type(4)));

#define SCALE_ 2.885390081777927f   // 2*log2(e): exp2(SCALE*x) == e^{2x}

// ---------------------------------------------------------------------------
// Kernel 1: EW[v][h] = 2*log2e*(sum_d E[v][d]*W[d][h] + b[h])
// ---------------------------------------------------------------------------
__global__ __launch_bounds__(256) void ew_kernel(const float* __restrict__ E,
                                                 const float* __restrict__ W,
                                                 const float* __restrict__ bias,
                                                 float* __restrict__ EW) {
    int idx = blockIdx.x * 256 + threadIdx.x;   // 0 .. V_*H_
    if (idx >= V_ * H_) return;
    int h = idx & (H_ - 1);
    int v = idx >> 6;
    float acc = bias[h];
    const float* Erow = E + v * D_;
    #pragma unroll 4
    for (int d = 0; d < D_; ++d) {
        acc = fmaf(Erow[d], W[d * H_ + h], acc);
    }
    EW[idx] = SCALE_ * acc;
}

// ---------------------------------------------------------------------------
// Kernel 2: RNN, one wave per batch element — R10 FINAL (session best:
// 318.7-320.8 us total, rnn 248.8-252.5 us = 583 cyc/step; reproduced 2x).
// STRUCTURAL FLOOR, bracketed by 7 HW-measured step variants:
//   grouped-readlane 583 | paired-readlane 623 | all-LDS 666 |
//   4-wave coop 719 | DPP systolic 743 | MFMA (16x16x32 bf16-split) 758 |
//   hybrid VALU+DS 915 cyc/step
// plus: NE>1 per wave provably non-winning at B == CU count (R8);
// barrier cooperation loses to its own round-trip (R14); MFMA keeps the
// LDS round-trip + 6-deep dependent-MFMA latency on the chain (R17).
// The h->h serial chain admits no cheaper 64-wide broadcast+reduce on this
// hardware; wall = T*583/2.4GHz + ew/launch ~= 319 us. Latency-bound floor
// (VALUBusy 19%, HBM 0.3% -- neither pipe saturated; the chain is).
// Key structures (each HW-verified):
//  - U pinned in 64 VGPRs: "+v" pin over all 16 f32x4 at init AND in-loop
//    (the ONLY pin shape that holds; single-op or input-only pins break)
//  - group-of-8 readlanes into 8 simultaneously-live SGPRs ("+s" 8-op pin)
//    then 8 FMAs: producer->consumer distance >= 8 insts covers the
//    VALU-writes-SGPR hazard; no SGPR recycling WAR
//  - padded sh_tok (no tail guard), 2-step EW prefetch pipeline
//  - clampless tanh: hn = 1 - 2*rcp(exp2(SCALE*x)+1); inf->1, 0->-1
// ---------------------------------------------------------------------------
__device__ __forceinline__ float readlane_f(float v, int lane) {
    return __uint_as_float(__builtin_amdgcn_readlane(__float_as_uint(v), lane));
}

__global__ __launch_bounds__(64, 1) void rnn_kernel(const int* __restrict__ tokens,
                                                    const float* __restrict__ EW,
                                                    const float* __restrict__ U,
                                                    const float* __restrict__ Wd,
                                                    const float* __restrict__ bd,
                                                    float* __restrict__ out) {
    const int b = blockIdx.x;     // batch element
    const int j = threadIdx.x;    // 0..63 : hidden unit

    __shared__ int sh_tok[T_ + 2];   // 4 KB + pad (kills tail guard)

    // --- (2*log2e)*U column j -> 16 float4 (64 VGPRs). Coalesced. ---
    f32x4 uq[16];
    #pragma unroll
    for (int c = 0; c < 16; ++c) {
        uq[c][0] = SCALE_ * U[(4 * c + 0) * H_ + j];
        uq[c][1] = SCALE_ * U[(4 * c + 1) * H_ + j];
        uq[c][2] = SCALE_ * U[(4 * c + 2) * H_ + j];
        uq[c][3] = SCALE_ * U[(4 * c + 3) * H_ + j];
    }
    // SINGLE pin: all 64 values live in VGPRs at once.
    asm volatile("" : "+v"(uq[0]), "+v"(uq[1]), "+v"(uq[2]), "+v"(uq[3]),
                      "+v"(uq[4]), "+v"(uq[5]), "+v"(uq[6]), "+v"(uq[7]),
                      "+v"(uq[8]), "+v"(uq[9]), "+v"(uq[10]), "+v"(uq[11]),
                      "+v"(uq[12]), "+v"(uq[13]), "+v"(uq[14]), "+v"(uq[15]));

    const int* tok = tokens + b * T_;
    #pragma unroll
    for (int k = 0; k < T_ / H_; ++k) {
        sh_tok[k * H_ + j] = tok[k * H_ + j];    // coalesced
    }
    if (j < 2) sh_tok[T_ + j] = 0;               // pad
    __syncthreads();

    float h = 0.f;
    float pooled = 0.f;

    // 2-step-deep xw prefetch pipeline (covers L2 latency of EW gather)
    int2 tkA = *(const int2*)&sh_tok[0];
    float xw0 = EW[tkA.x * H_ + j];
    float xw1 = EW[tkA.y * H_ + j];

    // one group: 8 hazard-free readlanes (distinct SGPRs) then 8 FMAs
    #define DOT_GROUP(g)                                                 \
    {                                                                    \
        float s0 = readlane_f(h, 8 * (g) + 0);                           \
        float s1 = readlane_f(h, 8 * (g) + 1);                           \
        float s2 = readlane_f(h, 8 * (g) + 2);                           \
        float s3 = readlane_f(h, 8 * (g) + 3);                           \
        float s4 = readlane_f(h, 8 * (g) + 4);                           \
        float s5 = readlane_f(h, 8 * (g) + 5);                           \
        float s6 = readlane_f(h, 8 * (g) + 6);                           \
        float s7 = readlane_f(h, 8 * (g) + 7);                           \
        asm volatile("" : "+s"(s0), "+s"(s1), "+s"(s2), "+s"(s3),        \
                          "+s"(s4), "+s"(s5), "+s"(s6), "+s"(s7));       \
        a0 = fmaf(s0, uq[2 * (g) + 0][0], a0);                           \
        a1 = fmaf(s1, uq[2 * (g) + 0][1], a1);                           \
        a2 = fmaf(s2, uq[2 * (g) + 0][2], a2);                           \
        a3 = fmaf(s3, uq[2 * (g) + 0][3], a3);                           \
        a0 = fmaf(s4, uq[2 * (g) + 1][0], a0);                           \
        a1 = fmaf(s5, uq[2 * (g) + 1][1], a1);                           \
        a2 = fmaf(s6, uq[2 * (g) + 1][2], a2);                           \
        a3 = fmaf(s7, uq[2 * (g) + 1][3], a3);                           \
    }

    // one recurrence step: grouped hazard-free broadcast + pinned-reg U
    #define RNN_STEP(tokv, xwv)                                          \
    {                                                                    \
        float a0 = (xwv), a1 = 0.f, a2 = 0.f, a3 = 0.f;                  \
        DOT_GROUP(0) DOT_GROUP(1) DOT_GROUP(2) DOT_GROUP(3)              \
        DOT_GROUP(4) DOT_GROUP(5) DOT_GROUP(6) DOT_GROUP(7)              \
        float x2 = (a0 + a1) + (a2 + a3);                                \
        float ef = __builtin_amdgcn_exp2f(x2);                           \
        float r = __builtin_amdgcn_rcpf(ef + 1.f);                       \
        float hn = fmaf(-2.f, r, 1.f);                                   \
        h = ((tokv) != 0) ? hn : h;                                      \
        pooled += h;                                                     \
    }

    for (int t = 0; t < T_; t += 2) {
        // in-loop pin: any uq spill would force an in-loop reload.
        asm volatile("" :: "v"(uq[0]), "v"(uq[1]), "v"(uq[2]), "v"(uq[3]),
                           "v"(uq[4]), "v"(uq[5]), "v"(uq[6]), "v"(uq[7]),
                           "v"(uq[8]), "v"(uq[9]), "v"(uq[10]), "v"(uq[11]),
                           "v"(uq[12]), "v"(uq[13]), "v"(uq[14]), "v"(uq[15]));

        // prefetch steps t+2, t+3 (pad makes the tail read safe: EW[0])
        int2 tkB = *(const int2*)&sh_tok[t + 2];
        float xw2 = EW[tkB.x * H_ + j];
        float xw3 = EW[tkB.y * H_ + j];

        RNN_STEP(tkA.x, xw0);
        RNN_STEP(tkA.y, xw1);

        tkA = tkB;
        xw0 = xw2;
        xw1 = xw3;
    }
    #undef RNN_STEP
    #undef DOT_GROUP

    // ---- epilogue: pooled mean -> dense(2) -> sigmoid ----
    float p = pooled * (1.0f / (float)T_);
    float v0 = p * Wd[j * C_ + 0];
    float v1 = p * Wd[j * C_ + 1];
    #pragma unroll
    for (int off = 32; off >= 1; off >>= 1) {
        v0 += __shfl_down(v0, off, 64);
        v1 += __shfl_down(v1, off, 64);
    }
    if (j == 0) {
        float l0 = v0 + bd[0];
        float l1 = v1 + bd[1];
        out[b * C_ + 0] = 1.f / (1.f + __expf(-l0));
        out[b * C_ + 1] = 1.f / (1.f + __expf(-l1));
    }
}

// ---------------------------------------------------------------------------
extern "C" void kernel_launch(void* const* d_in, const int* in_sizes, int n_in,
                              void* d_out, int out_size, void* d_ws, size_t ws_size,
                              hipStream_t stream) {
    const int*   tokens = (const int*)  d_in[0];  // [B,T] int32
    const float* E      = (const float*)d_in[1];  // [V,D]
    const float* W      = (const float*)d_in[2];  // [D,H]
    const float* U      = (const float*)d_in[3];  // [H,H]
    const float* bias   = (const float*)d_in[4];  // [H]
    const float* Wd     = (const float*)d_in[5];  // [H,C]
    const float* bd     = (const float*)d_in[6];  // [C]
    float* out = (float*)d_out;                   // [B,C]
    float* EW  = (float*)d_ws;                    // [V,H] scratch: 1.28 MB

    ew_kernel<<<(V_ * H_ + 255) / 256, 256, 0, stream>>>(E, W, bias, EW);
    rnn_kernel<<<B_, H_, 0, stream>>>(tokens, EW, U, Wd, bd, out);
}